// Round 1
// baseline (3984.403 us; speedup 1.0000x reference)
//
#include <hip/hip_runtime.h>
#include <cstddef>

constexpr int kVocab = 50000;
constexpr int kD = 256;
constexpr int kE = 4096;
constexpr int kS = 9;
constexpr int kA = 4;
constexpr int kOrders = 3;

// ---------------- init: var0 = var1 = 1 ----------------
__global__ __launch_bounds__(256) void init_kernel(float* __restrict__ var0,
                                                   float* __restrict__ var1) {
  size_t i = (size_t)blockIdx.x * 256 + threadIdx.x;
  var0[i] = 1.0f;
  var1[i] = 1.0f;
}

// ---------------- encoder front: pooled + out_tok + layernorm -> h ----------------
// one block per edge e, 256 threads = one per d
__global__ __launch_bounds__(256) void h_kernel(
    const float* __restrict__ node_emb, const float* __restrict__ var1,
    const int* __restrict__ input_ids, const float* __restrict__ input_mask,
    const int* __restrict__ var_in_mask, const int* __restrict__ vib,
    const int* __restrict__ out_pos, const float* __restrict__ ln_g,
    const float* __restrict__ ln_b, float* __restrict__ h) {
  const int e = blockIdx.x;
  const int d = threadIdx.x;
  const int op = out_pos[e];
  float acc = 0.f, msum = 0.f, tok = 0.f;
  for (int s = 0; s < kS; ++s) {
    const int idx = s * kE + e;
    const float mk = input_mask[idx];
    const float* src;
    if (var_in_mask[idx] >= 0) {
      int r = vib[idx];
      r = r < 0 ? 0 : (r > kE - 1 ? kE - 1 : r);
      src = var1 + (size_t)r * kD;
    } else {
      src = node_emb + (size_t)input_ids[idx] * kD;
    }
    const float val = src[d];
    acc += mk * val;
    msum += mk;
    if (s == op) tok = val;
  }
  float x = acc / fmaxf(msum, 1.0f) + tok;
  // block reduce sum & sumsq over 256 lanes (4 waves)
  float sum = x, sumsq = x * x;
#pragma unroll
  for (int off = 32; off > 0; off >>= 1) {
    sum += __shfl_down(sum, off);
    sumsq += __shfl_down(sumsq, off);
  }
  __shared__ float r0[4], r1[4];
  const int wid = threadIdx.x >> 6;
  if ((threadIdx.x & 63) == 0) { r0[wid] = sum; r1[wid] = sumsq; }
  __syncthreads();
  const float tot = r0[0] + r0[1] + r0[2] + r0[3];
  const float totsq = r1[0] + r1[1] + r1[2] + r1[3];
  const float mu = tot * (1.0f / kD);
  const float var = totsq * (1.0f / kD) - mu * mu;
  h[(size_t)e * kD + d] = (x - mu) * rsqrtf(var + 1e-5f) * ln_g[d] + ln_b[d];
}

// ---------------- MLP: enc = sigmoid(relu(h@W1+b1)@W2+b2) ----------------
// RB rows per block; thread d owns output column d for all RB rows.
constexpr int kRB = 8;
__global__ __launch_bounds__(256) void mlp_kernel(
    const float* __restrict__ h, const float* __restrict__ W1,
    const float* __restrict__ b1, const float* __restrict__ W2,
    const float* __restrict__ b2, float* __restrict__ enc) {
  __shared__ float hs[kRB][kD];
  __shared__ float ts[kRB][kD];
  const int e0 = blockIdx.x * kRB;
  const int d = threadIdx.x;
  for (int i = threadIdx.x; i < kRB * kD; i += 256)
    ((float*)hs)[i] = h[(size_t)e0 * kD + i];
  __syncthreads();
  float acc[kRB];
#pragma unroll
  for (int r = 0; r < kRB; ++r) acc[r] = 0.f;
  for (int k = 0; k < kD; ++k) {
    const float w = W1[k * kD + d];
#pragma unroll
    for (int r = 0; r < kRB; ++r) acc[r] += hs[r][k] * w;
  }
  const float bb1 = b1[d];
#pragma unroll
  for (int r = 0; r < kRB; ++r) ts[r][d] = fmaxf(acc[r] + bb1, 0.f);
  __syncthreads();
#pragma unroll
  for (int r = 0; r < kRB; ++r) acc[r] = 0.f;
  for (int k = 0; k < kD; ++k) {
    const float w = W2[k * kD + d];
#pragma unroll
    for (int r = 0; r < kRB; ++r) acc[r] += ts[r][k] * w;
  }
  const float bb2 = b2[d];
#pragma unroll
  for (int r = 0; r < kRB; ++r) {
    const float z = acc[r] + bb2;
    enc[(size_t)(e0 + r) * kD + d] = 1.0f / (1.0f + expf(-z));
  }
}

// ---------------- logic pass 1: var0/var1 set + negation (elementwise) ----------------
__global__ __launch_bounds__(256) void logic1_kernel(
    const float* __restrict__ enc, const int* __restrict__ orders,
    const int* __restrict__ ltypes, const int order, float* __restrict__ var0,
    const float* __restrict__ v1_in, float* __restrict__ v1_out) {
  const int e = blockIdx.x;
  const int d = threadIdx.x;
  const size_t i = (size_t)e * kD + d;
  float v1 = v1_in[i];
  if (orders[e] == order) {
    const float v = enc[i];
    var0[i] = v;
    v1 = (ltypes[e] == 1) ? 1.0f - v : v;
  }
  v1_out[i] = v1;
}

// ---------------- conjunction: prod over valid fan-in (neutral 1), slot0 = var0 ----------------
__global__ __launch_bounds__(256) void conj_kernel(
    const float* __restrict__ var0, const float* __restrict__ v1_in,
    float* __restrict__ v1_out, const int* __restrict__ orders,
    const int* __restrict__ ltypes, const int* __restrict__ logic_in_ids,
    const int* __restrict__ lib, const int order) {
  const int e = blockIdx.x;
  const int d = threadIdx.x;
  const size_t i = (size_t)e * kD + d;
  float out = v1_in[i];
  if (orders[e] == order && ltypes[e] == 2) {
    float p = var0[i];
    for (int a = 1; a < kA; ++a) {
      if (logic_in_ids[a * kE + e] >= 0) {
        int r = lib[a * kE + e];
        r = r < 0 ? 0 : (r > kE - 1 ? kE - 1 : r);
        p *= v1_in[(size_t)r * kD + d];
      }
    }
    out = p;
  }
  v1_out[i] = out;
}

// ---------------- disjunction: 1 - prod(1 - x) (neutral 0), slot0 = var0 ----------------
__global__ __launch_bounds__(256) void disj_kernel(
    const float* __restrict__ var0, const float* __restrict__ v1_in,
    float* __restrict__ v1_out, const int* __restrict__ orders,
    const int* __restrict__ ltypes, const int* __restrict__ logic_in_ids,
    const int* __restrict__ lib, const int order) {
  const int e = blockIdx.x;
  const int d = threadIdx.x;
  const size_t i = (size_t)e * kD + d;
  float out = v1_in[i];
  if (orders[e] == order && ltypes[e] == 3) {
    float p = 1.0f - var0[i];
    for (int a = 1; a < kA; ++a) {
      if (logic_in_ids[a * kE + e] >= 0) {
        int r = lib[a * kE + e];
        r = r < 0 ? 0 : (r > kE - 1 ? kE - 1 : r);
        p *= 1.0f - v1_in[(size_t)r * kD + d];
      }
    }
    out = 1.0f - p;
  }
  v1_out[i] = out;
}

// ---------------- scoring GEMM: logits[e][v] = sum_k var1[e][k] * node_emb[v][k] ----------------
constexpr int kBM = 32;
constexpr int kBN = 128;
constexpr int kKC = 64;
__global__ __launch_bounds__(256) void gemm_kernel(
    const float* __restrict__ A,   // var1 [E][D]
    const float* __restrict__ B,   // node_emb [VOCAB][D]
    float* __restrict__ C) {       // logits [E][VOCAB] (misaligned base: scalar stores)
  __shared__ float As[kD][kBM + 4];   // transposed: As[k][m]
  __shared__ float Bs[kKC][kBN + 4];  // transposed: Bs[k][n]
  const int t = threadIdx.x;
  const int eb = blockIdx.y * kBM;
  const int vb = blockIdx.x * kBN;
  // load full-K A tile, transposed
  for (int i = t; i < kBM * (kD / 4); i += 256) {
    const int m = i >> 6, kq = i & 63;
    const float4 v = ((const float4*)(A + (size_t)(eb + m) * kD))[kq];
    As[kq * 4 + 0][m] = v.x;
    As[kq * 4 + 1][m] = v.y;
    As[kq * 4 + 2][m] = v.z;
    As[kq * 4 + 3][m] = v.w;
  }
  const int tx = t & 31;  // col group: 4*tx .. 4*tx+3
  const int ty = t >> 5;  // row group: 4*ty .. 4*ty+3
  float acc[4][4];
#pragma unroll
  for (int i2 = 0; i2 < 4; ++i2)
#pragma unroll
    for (int j = 0; j < 4; ++j) acc[i2][j] = 0.f;

  for (int kc = 0; kc < kD; kc += kKC) {
    __syncthreads();  // also covers As on first pass, protects Bs reuse after
    for (int i = t; i < kBN * (kKC / 4); i += 256) {
      const int n = i >> 4, kq = i & 15;
      const int v = vb + n;
      float4 val = make_float4(0.f, 0.f, 0.f, 0.f);
      if (v < kVocab) val = ((const float4*)(B + (size_t)v * kD + kc))[kq];
      Bs[kq * 4 + 0][n] = val.x;
      Bs[kq * 4 + 1][n] = val.y;
      Bs[kq * 4 + 2][n] = val.z;
      Bs[kq * 4 + 3][n] = val.w;
    }
    __syncthreads();
#pragma unroll
    for (int k = 0; k < kKC; ++k) {
      const float4 a4 = *(const float4*)&As[kc + k][ty * 4];
      const float4 b4 = *(const float4*)&Bs[k][tx * 4];
      const float a[4] = {a4.x, a4.y, a4.z, a4.w};
      const float b[4] = {b4.x, b4.y, b4.z, b4.w};
#pragma unroll
      for (int i2 = 0; i2 < 4; ++i2)
#pragma unroll
        for (int j = 0; j < 4; ++j) acc[i2][j] += a[i2] * b[j];
    }
  }
#pragma unroll
  for (int i2 = 0; i2 < 4; ++i2) {
    const int e = eb + ty * 4 + i2;
    float* out = C + (size_t)e * kVocab;
#pragma unroll
    for (int j = 0; j < 4; ++j) {
      const int v = vb + tx * 4 + j;
      if (v < kVocab) out[v] = acc[i2][j];
    }
  }
}

// ---------------- per-row softmax stats + soft-label CE ----------------
__global__ __launch_bounds__(256) void stats_kernel(
    const float* __restrict__ logits, const int* __restrict__ answers,
    const int* __restrict__ mask_type, float* __restrict__ loss_rows) {
  const int e = blockIdx.x;
  const int t = threadIdx.x;
  const float* row = logits + (size_t)e * kVocab;
  const int ans = answers[e];
  __shared__ float sh_zans;
  float m = -3.4e38f, s = 0.f, sz = 0.f;
  for (int v = t; v < kVocab; v += 256) {
    const float z = row[v];
    sz += z;
    if (v == ans) sh_zans = z;
    if (z > m) {
      s = s * expf(m - z) + 1.0f;
      m = z;
    } else {
      s += expf(z - m);
    }
  }
#pragma unroll
  for (int off = 32; off > 0; off >>= 1) {
    const float m2 = __shfl_down(m, off);
    const float s2 = __shfl_down(s, off);
    sz += __shfl_down(sz, off);
    const float M = fmaxf(m, m2);
    s = s * expf(m - M) + s2 * expf(m2 - M);
    m = M;
  }
  __shared__ float m4[4], s4[4], sz4[4];
  const int wid = t >> 6;
  if ((t & 63) == 0) { m4[wid] = m; s4[wid] = s; sz4[wid] = sz; }
  __syncthreads();
  if (t == 0) {
    float M = m4[0], S = s4[0];
    float SZ = sz4[0] + sz4[1] + sz4[2] + sz4[3];
    for (int w = 1; w < 4; ++w) {
      const float M2 = fmaxf(M, m4[w]);
      S = S * expf(M - M2) + s4[w] * expf(m4[w] - M2);
      M = M2;
    }
    const float lse = M + logf(S);
    const float soft = (mask_type[e] > 0) ? 0.9f : 1.0f;
    const float zans = sh_zans;
    const float lab = soft * zans + (1.0f - soft) * (SZ - zans) * (1.0f / (kVocab - 1));
    loss_rows[e] = lse - lab;
  }
}

__global__ __launch_bounds__(256) void final_kernel(const float* __restrict__ loss_rows,
                                                    float* __restrict__ out) {
  float s = 0.f;
  for (int i = threadIdx.x; i < kE; i += 256) s += loss_rows[i];
#pragma unroll
  for (int off = 32; off > 0; off >>= 1) s += __shfl_down(s, off);
  __shared__ float r[4];
  if ((threadIdx.x & 63) == 0) r[threadIdx.x >> 6] = s;
  __syncthreads();
  if (threadIdx.x == 0) out[0] = (r[0] + r[1] + r[2] + r[3]) * (1.0f / kE);
}

// ---------------- host ----------------
extern "C" void kernel_launch(void* const* d_in, const int* in_sizes, int n_in,
                              void* d_out, int out_size, void* d_ws, size_t ws_size,
                              hipStream_t stream) {
  const float* node_emb = (const float*)d_in[0];
  const int* input_ids = (const int*)d_in[1];
  const float* input_mask = (const float*)d_in[2];
  const int* edge_orders = (const int*)d_in[3];
  const int* var_in_mask = (const int*)d_in[4];
  const int* vib = (const int*)d_in[5];
  const int* out_pos = (const int*)d_in[6];
  const int* logic_in_ids = (const int*)d_in[7];
  const int* lib = (const int*)d_in[8];
  const int* logic_types = (const int*)d_in[9];
  const int* answers = (const int*)d_in[10];
  const int* mask_type = (const int*)d_in[11];
  const float* W1 = (const float*)d_in[12];
  const float* b1 = (const float*)d_in[13];
  const float* W2 = (const float*)d_in[14];
  const float* b2 = (const float*)d_in[15];
  const float* ln_g = (const float*)d_in[16];
  const float* ln_b = (const float*)d_in[17];

  float* out = (float*)d_out;
  float* logits = out + 1;  // [E][VOCAB]

  const size_t ED = (size_t)kE * kD;
  float* ws = (float*)d_ws;
  float* var0 = ws;             // [E][D]
  float* v1a = ws + ED;         // current var1
  float* v1b = ws + 2 * ED;     // after logic1
  float* v1c = ws + 3 * ED;     // after conj
  float* h = ws + 4 * ED;       // [E][D]
  float* enc = ws + 5 * ED;     // [E][D]
  float* loss_rows = ws + 6 * ED;  // [E]

  init_kernel<<<kE * kD / 256, 256, 0, stream>>>(var0, v1a);

  for (int o = 0; o < kOrders; ++o) {
    h_kernel<<<kE, 256, 0, stream>>>(node_emb, v1a, input_ids, input_mask,
                                     var_in_mask, vib, out_pos, ln_g, ln_b, h);
    mlp_kernel<<<kE / kRB, 256, 0, stream>>>(h, W1, b1, W2, b2, enc);
    logic1_kernel<<<kE, 256, 0, stream>>>(enc, edge_orders, logic_types, o,
                                          var0, v1a, v1b);
    conj_kernel<<<kE, 256, 0, stream>>>(var0, v1b, v1c, edge_orders, logic_types,
                                        logic_in_ids, lib, o);
    disj_kernel<<<kE, 256, 0, stream>>>(var0, v1c, v1a, edge_orders, logic_types,
                                        logic_in_ids, lib, o);
  }

  dim3 ggrid((kVocab + kBN - 1) / kBN, kE / kBM);
  gemm_kernel<<<ggrid, 256, 0, stream>>>(v1a, node_emb, logits);

  stats_kernel<<<kE, 256, 0, stream>>>(logits, answers, mask_type, loss_rows);
  final_kernel<<<1, 256, 0, stream>>>(loss_rows, out);
}